// Round 22
// baseline (338.048 us; speedup 1.0000x reference)
//
#include <hip/hip_runtime.h>

#define K1 3072
#define N1 1024
#define NCOL 50

typedef float  f32x4  __attribute__((ext_vector_type(4)));
typedef short  short8 __attribute__((ext_vector_type(8)));

#define GLD16(g, l)                                                        \
  __builtin_amdgcn_global_load_lds(                                        \
      (const __attribute__((address_space(1))) void*)(g),                  \
      (__attribute__((address_space(3))) void*)(l), 16, 0, 0)

#define MFMA_BF16(a, b, c) __builtin_amdgcn_mfma_f32_16x16x32_bf16(a, b, c, 0, 0, 0)
#define SBAR()  __builtin_amdgcn_sched_barrier(0)

__device__ inline unsigned bfr(float f) {          // round-half-up bf16 bits in lo16
  return (__builtin_bit_cast(unsigned, f) + 0x8000u) >> 16;
}
__device__ inline short f2bf(float f) { return (short)bfr(f); }
__device__ inline short8 cvt8(float4 a, float4 b) {
  short8 r;
  r[0] = f2bf(a.x); r[1] = f2bf(a.y); r[2] = f2bf(a.z); r[3] = f2bf(a.w);
  r[4] = f2bf(b.x); r[5] = f2bf(b.y); r[6] = f2bf(b.z); r[7] = f2bf(b.w);
  return r;
}

// ================= fused prep kernel: w1t (768) | w2t (16) | xcvt (2048) =================
__global__ __launch_bounds__(256)
void prep_kernel(const float* __restrict__ X, short* __restrict__ Xb,
                 const float* __restrict__ W1, short* __restrict__ W1T,
                 const float* __restrict__ W2, short* __restrict__ W2T) {
  __shared__ float tile[64 * 65];
  const int b = blockIdx.x, t = threadIdx.x;

  if (b < 768) {                       // ---- W1T: 64x64 LDS-tiled transpose ----
    const int k0 = (b >> 4) * 64, n0 = (b & 15) * 64;
#pragma unroll
    for (int i = 0; i < 16; ++i) {
      const int e = t + i * 256, r = e >> 6, c = e & 63;
      tile[r * 65 + c] = W1[(size_t)(k0 + r) * N1 + n0 + c];
    }
    __syncthreads();
#pragma unroll
    for (int i = 0; i < 16; ++i) {
      const int e = t + i * 256, kx = e & 63, ny = e >> 6;
      W1T[(size_t)(n0 + ny) * K1 + k0 + kx] = f2bf(tile[kx * 65 + ny]);
    }
  } else if (b < 784) {                // ---- W2T: [64 padded cols][1024] ----
    const int idx = (b - 768) * 256 + t;
    for (int e = idx; e < 64 * N1; e += 16 * 256) {
      const int c = e >> 10, k = e & 1023;
      const float v = (c < NCOL) ? W2[(size_t)k * NCOL + c] : 0.f;
      W2T[(size_t)c * N1 + k] = f2bf(v);
    }
  } else {                             // ---- Xb: f32 -> bf16 bulk convert ----
    size_t i = ((size_t)(b - 784) * 256 + t) * 8;
    const size_t stride = (size_t)2048 * 256 * 8;   // 2048 xcvt blocks
#pragma unroll 4
    for (int it = 0; it < 24; ++it, i += stride) {  // 24*stride = 32768*3072
      float4 u = *(const float4*)(X + i);
      float4 v = *(const float4*)(X + i + 4);
      *(short8*)(Xb + i) = cvt8(u, v);
    }
  }
}

// == path 2: 256x256, 16 waves (4/SIMD), whole-tile counted-vmcnt (R19, session best) ==
#define BK2 64
#define NIT (K1 / BK2)      // 48
#define ASLOT (256 * 64)    // shorts per slot per tensor (32 KB)
#define SH2 264             // epilogue stride (shorts)

struct __align__(16) Smem2 {
  union {
    struct { short A[2][ASLOT]; short B[2][ASLOT]; } s;    // 128 KB
    struct { short h[128 * SH2]; short w2t[64 * SH2]; } e; // 101.4 KB
  } u;
};

__global__ __launch_bounds__(1024, 4)
void hoi_fused3(const short* __restrict__ Xb, const short* __restrict__ W1T,
                const float* __restrict__ B1, const short* __restrict__ W2T,
                const float* __restrict__ B2, float* __restrict__ OUT) {
  __shared__ Smem2 sm;
  const int tid  = threadIdx.x;
  const int lane = tid & 63, wid = tid >> 6;      // 16 waves
  const int wr = wid >> 2, wc = wid & 3;          // wave = 64x64 quadrant (4x4 grid)
  const int l15 = lane & 15, g = lane >> 4, l7 = l15 & 7;

  // bijective XCD-grouped swizzle: 512 wgs, 64/XCD, n fastest
  const int bid  = blockIdx.x;
  const int gidx = (bid & 7) * 64 + (bid >> 3);
  const int m_blk = gidx >> 2, n_blk = gidx & 3;
  const int m0 = m_blk * 256, n0 = n_blk * 256;

  // staging: 1 gload16/wave/unit; wave covers rows wid*8..wid*8+7 of each half
  const int srow  = lane >> 3;
  const int sslot = (lane & 7) ^ srow;            // both-sides swizzle (16B slots)
  const short* aP = Xb  + (size_t)(m0 + wid * 8 + srow) * K1 + sslot * 8;
  const short* bP = W1T + (size_t)(n0 + wid * 8 + srow) * K1 + sslot * 8;
  const int dA = (wid * 8) * 64;                  // wave-uniform LDS dest (shorts)

#define I_A0(kt, sl) GLD16(aP + (size_t)(kt) * BK2,                    &sm.u.s.A[sl][dA])
#define I_A1(kt, sl) GLD16(aP + (size_t)128 * K1 + (size_t)(kt) * BK2, &sm.u.s.A[sl][dA + 8192])
#define I_B0(kt, sl) GLD16(bP + (size_t)(kt) * BK2,                    &sm.u.s.B[sl][dA])
#define I_B1(kt, sl) GLD16(bP + (size_t)128 * K1 + (size_t)(kt) * BK2, &sm.u.s.B[sl][dA + 8192])

  // frag-read bases (swizzled slots; row&7 == l7)
  const int aRd = (wr * 64 + l15) * 64;
  const int bRd = (wc * 64 + l15) * 64;
  const int sk0 = ((g)     ^ l7) * 8;
  const int sk1 = ((4 | g) ^ l7) * 8;

  float b1v[4];
#pragma unroll
  for (int nf = 0; nf < 4; ++nf) b1v[nf] = B1[n0 + wc * 64 + nf * 16 + l15];

  f32x4 acc[4][4] = {};

  // prologue: tile 0 (order-insensitive: whole-tile retirement), full drain
  I_A0(0, 0); I_B0(0, 0); I_B1(0, 0); I_A1(0, 0);
  asm volatile("s_waitcnt vmcnt(0)" ::: "memory");
  __builtin_amdgcn_s_barrier();

  for (int t = 0; t < NIT; ++t) {
    const int s  = t & 1, sx = s ^ 1;
    const int tn = (t + 1 < NIT) ? t + 1 : NIT - 1;   // clamped; junk never read

    __builtin_amdgcn_s_barrier();                     // #A: seals reads of tile t-1
    I_A0(tn, sx);                                     // slot sx free since #A
    SBAR();
    asm volatile("s_waitcnt vmcnt(1)" ::: "memory");  // retire ALL of tile t; keep A0(t+1)
    __builtin_amdgcn_s_barrier();                     // #B: tile t visible block-wide
    SBAR();
    I_A1(tn, sx);
    I_B0(tn, sx);
    I_B1(tn, sx);
    SBAR();

    short8 a_[2][2], b_[4][2];

    // ---- reads: A-lo (mf0-1) + B-all; Q0 ----
#pragma unroll
    for (int mf = 0; mf < 2; ++mf) {
      a_[mf][0] = *(const short8*)&sm.u.s.A[s][aRd + mf * 1024 + sk0];
      a_[mf][1] = *(const short8*)&sm.u.s.A[s][aRd + mf * 1024 + sk1];
    }
#pragma unroll
    for (int nf = 0; nf < 4; ++nf) {
      b_[nf][0] = *(const short8*)&sm.u.s.B[s][bRd + nf * 1024 + sk0];
      b_[nf][1] = *(const short8*)&sm.u.s.B[s][bRd + nf * 1024 + sk1];
    }
    asm volatile("s_waitcnt lgkmcnt(0)" ::: "memory");
    SBAR();
    __builtin_amdgcn_s_setprio(1);
#pragma unroll
    for (int mf = 0; mf < 2; ++mf)
#pragma unroll
      for (int nf = 0; nf < 4; ++nf) {
        acc[mf][nf] = MFMA_BF16(a_[mf][0], b_[nf][0], acc[mf][nf]);
        acc[mf][nf] = MFMA_BF16(a_[mf][1], b_[nf][1], acc[mf][nf]);
      }
    __builtin_amdgcn_s_setprio(0);
    SBAR();

    // ---- reads: A-hi (mf2-3) into same regs; Q1 ----
#pragma unroll
    for (int mf = 0; mf < 2; ++mf) {
      a_[mf][0] = *(const short8*)&sm.u.s.A[s][aRd + (2 + mf) * 1024 + sk0];
      a_[mf][1] = *(const short8*)&sm.u.s.A[s][aRd + (2 + mf) * 1024 + sk1];
    }
    asm volatile("s_waitcnt lgkmcnt(0)" ::: "memory");
    SBAR();
    __builtin_amdgcn_s_setprio(1);
#pragma unroll
    for (int mf = 0; mf < 2; ++mf)
#pragma unroll
      for (int nf = 0; nf < 4; ++nf) {
        acc[2 + mf][nf] = MFMA_BF16(a_[mf][0], b_[nf][0], acc[2 + mf][nf]);
        acc[2 + mf][nf] = MFMA_BF16(a_[mf][1], b_[nf][1], acc[2 + mf][nf]);
      }
    __builtin_amdgcn_s_setprio(0);
    SBAR();
  }
#undef I_A0
#undef I_A1
#undef I_B0
#undef I_B1

  // ---- epilogue: two 128-row phases, 16 waves ----
  for (int ph = 0; ph < 2; ++ph) {
    __syncthreads();   // full drain (vmcnt0+lgkm0): junk DMA landed; prior reads sealed

    if ((wr >> 1) == ph) {   // 8 waves (wr in {2ph,2ph+1}) write their 64x64 quadrant
      const int rbase = (wr & 1) * 64;
#pragma unroll
      for (int mf = 0; mf < 4; ++mf)
#pragma unroll
        for (int nf = 0; nf < 4; ++nf) {
          const int c = wc * 64 + nf * 16 + l15;
#pragma unroll
          for (int j = 0; j < 4; ++j) {
            const int r = rbase + mf * 16 + g * 4 + j;
            sm.u.e.h[r * SH2 + c] = f2bf(fmaxf(acc[mf][nf][j] + b1v[nf], 0.f));
          }
        }
    }
    if (ph == 0) {     // stage w2t[64][256] slice: 1024 threads x 16 shorts
      const int c = tid >> 4, k0c = (tid & 15) * 16;
      *(short8*)&sm.u.e.w2t[c * SH2 + k0c + 0] =
          *(const short8*)&W2T[(size_t)c * N1 + n0 + k0c + 0];
      *(short8*)&sm.u.e.w2t[c * SH2 + k0c + 8] =
          *(const short8*)&W2T[(size_t)c * N1 + n0 + k0c + 8];
    }
    __syncthreads();

    // GEMM2: 128 rows x 50 cols, K = 256; wave = 16 rows x 32-col half
    const int rg = wid >> 1, nh = wid & 1;
    f32x4 acc2[2] = {};
#pragma unroll
    for (int ks = 0; ks < 8; ++ks) {
      const short8 a2 = *(const short8*)&sm.u.e.h[(rg * 16 + l15) * SH2 + ks * 32 + g * 8];
#pragma unroll
      for (int nfl = 0; nfl < 2; ++nfl) {
        const short8 b2 =
            *(const short8*)&sm.u.e.w2t[(nh * 32 + nfl * 16 + l15) * SH2 + ks * 32 + g * 8];
        acc2[nfl] = MFMA_BF16(a2, b2, acc2[nfl]);
      }
    }
#pragma unroll
    for (int nfl = 0; nfl < 2; ++nfl) {
      const int c = nh * 32 + nfl * 16 + l15;
      if (c < NCOL) {
#pragma unroll
        for (int j = 0; j < 4; ++j) {
          const int r = m0 + ph * 128 + rg * 16 + g * 4 + j;
          float v = acc2[nfl][j];
          if (n_blk == 0) v += B2[c];
          atomicAdd(&OUT[(size_t)r * NCOL + c], v);
        }
      }
    }
  }
}

// ================= path 0: R5 fallback (no ws) =================
#define BK 32
#define NSTEP (K1 / BK)
#define SAS 40
#define SHS 136

struct __align__(16) Smem0 {
  union {
    struct { short A[128 * SAS]; short BT[128 * SAS]; } s[2];
    struct { short h[64 * SHS]; short w2t[64 * SHS]; } e;
  } u;
};

__global__ __launch_bounds__(256, 3)
void hoi_fused0(const float* __restrict__ X, const float* __restrict__ W1,
                const float* __restrict__ B1, const float* __restrict__ W2,
                const float* __restrict__ B2, float* __restrict__ OUT) {
  __shared__ Smem0 sm;
  const int tid  = threadIdx.x;
  const int lane = tid & 63, wid = tid >> 6;
  const int wr = wid >> 1, wc = wid & 1;
  const int l15 = lane & 15, g = lane >> 4;
  const int bid   = blockIdx.x;
  const int xcd   = bid & 7, o = bid >> 3;
  const int m_blk = xcd * 32 + (o >> 3);
  const int n_blk = o & 7;
  const int m0 = m_blk * 128, n0 = n_blk * 128;

  const int arow = tid >> 1;
  const int akc  = (tid & 1) << 4;
  const float* aptr = X + (size_t)(m0 + arow) * K1 + akc;
  const int bk2 = tid >> 4, bcm = tid & 15;
  const float* bptr = W1 + (size_t)(2 * bk2) * N1 + n0 + bcm;

  float b1v[4];
#pragma unroll
  for (int nt = 0; nt < 4; ++nt) b1v[nt] = B1[n0 + wc * 64 + nt * 16 + l15];

  f32x4 acc[4][4] = {};
  float4 ra[4];
  float  rb0[8], rb1[8];
#pragma unroll
  for (int q = 0; q < 4; ++q) ra[q] = *(const float4*)(aptr + 4 * q);
#pragma unroll
  for (int i = 0; i < 8; ++i) { rb0[i] = bptr[16 * i]; rb1[i] = bptr[N1 + 16 * i]; }

  for (int step = 0; step < NSTEP; ++step) {
    const int cb = step & 1;
    const short8 av0 = cvt8(ra[0], ra[1]);
    const short8 av1 = cvt8(ra[2], ra[3]);
    unsigned bpk[8];
#pragma unroll
    for (int i = 0; i < 8; ++i)
      bpk[i] = bfr(rb0[i]) | ((__builtin_bit_cast(unsigned, rb1[i]) + 0x8000u) & 0xFFFF0000u);
    if (step + 1 < NSTEP) {
      const int k0v = (step + 1) * BK;
#pragma unroll
      for (int q = 0; q < 4; ++q) ra[q] = *(const float4*)(aptr + k0v + 4 * q);
      const float* bp = bptr + (size_t)k0v * N1;
#pragma unroll
      for (int i = 0; i < 8; ++i) { rb0[i] = bp[16 * i]; rb1[i] = bp[N1 + 16 * i]; }
    }
    *(short8*)&sm.u.s[cb].A[arow * SAS + akc + 0] = av0;
    *(short8*)&sm.u.s[cb].A[arow * SAS + akc + 8] = av1;
#pragma unroll
    for (int i = 0; i < 8; ++i)
      *(unsigned*)&sm.u.s[cb].BT[(bcm + 16 * i) * SAS + 2 * bk2] = bpk[i];

    asm volatile("s_waitcnt lgkmcnt(0)" ::: "memory");
    __builtin_amdgcn_s_barrier();
    __builtin_amdgcn_sched_barrier(0);

    short8 af[4];
#pragma unroll
    for (int mt = 0; mt < 4; ++mt)
      af[mt] = *(const short8*)&sm.u.s[cb].A[(wr * 64 + mt * 16 + l15) * SAS + g * 8];
#pragma unroll
    for (int nt = 0; nt < 4; ++nt) {
      short8 bfv = *(const short8*)&sm.u.s[cb].BT[(wc * 64 + nt * 16 + l15) * SAS + g * 8];
#pragma unroll
      for (int mt = 0; mt < 4; ++mt)
        acc[mt][nt] = MFMA_BF16(af[mt], bfv, acc[mt][nt]);
    }
  }

  for (int p = 0; p < 2; ++p) {
    __syncthreads();
    if (wr == p) {
#pragma unroll
      for (int mt = 0; mt < 4; ++mt)
#pragma unroll
        for (int nt = 0; nt < 4; ++nt) {
          const int c = wc * 64 + nt * 16 + l15;
#pragma unroll
          for (int j = 0; j < 4; ++j) {
            const int r = mt * 16 + g * 4 + j;
            sm.u.e.h[r * SHS + c] = f2bf(fmaxf(acc[mt][nt][j] + b1v[nt], 0.f));
          }
        }
    }
    if (p == 0) {
      const int kk = tid >> 1, ch = (tid & 1) * 32;
#pragma unroll
      for (int i = 0; i < 32; ++i) {
        const int c = ch + i;
        const float v = (c < NCOL) ? W2[(size_t)(n0 + kk) * NCOL + c] : 0.f;
        sm.u.e.w2t[c * SHS + kk] = f2bf(v);
      }
    }
    __syncthreads();

    f32x4 acc2[4] = {};
#pragma unroll
    for (int ks = 0; ks < 4; ++ks) {
      const short8 a2f = *(const short8*)&sm.u.e.h[(wid * 16 + l15) * SHS + ks * 32 + g * 8];
#pragma unroll
      for (int nt2 = 0; nt2 < 4; ++nt2) {
        const short8 b2f = *(const short8*)&sm.u.e.w2t[(nt2 * 16 + l15) * SHS + ks * 32 + g * 8];
        acc2[nt2] = MFMA_BF16(a2f, b2f, acc2[nt2]);
      }
    }
#pragma unroll
    for (int nt2 = 0; nt2 < 4; ++nt2) {
      const int c = nt2 * 16 + l15;
      if (c < NCOL) {
#pragma unroll
        for (int j = 0; j < 4; ++j) {
          const int r = m0 + p * 64 + wid * 16 + g * 4 + j;
          float v = acc2[nt2][j];
          if (n_blk == 0) v += B2[c];
          atomicAdd(&OUT[(size_t)r * NCOL + c], v);
        }
      }
    }
  }
}

extern "C" void kernel_launch(void* const* d_in, const int* in_sizes, int n_in,
                              void* d_out, int out_size, void* d_ws, size_t ws_size,
                              hipStream_t stream) {
  const float* X  = (const float*)d_in[0];
  const float* W1 = (const float*)d_in[1];
  const float* B1 = (const float*)d_in[2];
  const float* W2 = (const float*)d_in[3];
  const float* B2 = (const float*)d_in[4];
  float* OUT = (float*)d_out;

  const size_t XB_BYTES  = (size_t)32768 * K1 * 2;   // 201,326,592
  const size_t W1T_BYTES = (size_t)N1 * K1 * 2;      // 6,291,456
  const size_t W2T_BYTES = (size_t)64 * N1 * 2;      // 131,072

  hipMemsetAsync(d_out, 0, (size_t)out_size * sizeof(float), stream);

  if (ws_size >= XB_BYTES + W1T_BYTES + W2T_BYTES) {
    short* Xb  = (short*)d_ws;
    short* W1T = (short*)((char*)d_ws + XB_BYTES);
    short* W2T = (short*)((char*)d_ws + XB_BYTES + W1T_BYTES);
    hipLaunchKernelGGL(prep_kernel, dim3(2832), dim3(256), 0, stream,
                       X, Xb, W1, W1T, W2, W2T);
    hipLaunchKernelGGL(hoi_fused3, dim3(512), dim3(1024), 0, stream, Xb, W1T, B1, W2T, B2, OUT);
  } else {
    hipLaunchKernelGGL(hoi_fused0, dim3(2048), dim3(256), 0, stream, X, W1, B1, W2, B2, OUT);
  }
}

// Round 23
// 326.970 us; speedup vs baseline: 1.0339x; 1.0339x over previous
//
#include <hip/hip_runtime.h>

#define K1 3072
#define N1 1024
#define NCOL 50

typedef float  f32x4  __attribute__((ext_vector_type(4)));
typedef short  short8 __attribute__((ext_vector_type(8)));

#define GLD16(g, l)                                                        \
  __builtin_amdgcn_global_load_lds(                                        \
      (const __attribute__((address_space(1))) void*)(g),                  \
      (__attribute__((address_space(3))) void*)(l), 16, 0, 0)

#define MFMA_BF16(a, b, c) __builtin_amdgcn_mfma_f32_16x16x32_bf16(a, b, c, 0, 0, 0)
#define SBAR()  __builtin_amdgcn_sched_barrier(0)

__device__ inline unsigned bfr(float f) {          // round-half-up bf16 bits in lo16
  return (__builtin_bit_cast(unsigned, f) + 0x8000u) >> 16;
}
__device__ inline short f2bf(float f) { return (short)bfr(f); }
__device__ inline short8 cvt8(float4 a, float4 b) {
  short8 r;
  r[0] = f2bf(a.x); r[1] = f2bf(a.y); r[2] = f2bf(a.z); r[3] = f2bf(a.w);
  r[4] = f2bf(b.x); r[5] = f2bf(b.y); r[6] = f2bf(b.z); r[7] = f2bf(b.w);
  return r;
}

// ================= prep kernels =================
__global__ __launch_bounds__(512) void xcvt_kernel(const float* __restrict__ X,
                                                   short* __restrict__ Xb) {
  size_t i = ((size_t)blockIdx.x * 512 + threadIdx.x) * 8;
  const size_t stride = (size_t)2048 * 512 * 8;   // grid = 2048
#pragma unroll 4
  for (int it = 0; it < 12; ++it, i += stride) {  // 12 * stride = 32768*3072 exactly
    float4 u = *(const float4*)(X + i);
    float4 v = *(const float4*)(X + i + 4);
    *(short8*)(Xb + i) = cvt8(u, v);
  }
}

__global__ __launch_bounds__(256) void w1t_kernel(const float* __restrict__ W1,
                                                  short* __restrict__ W1T) {
  __shared__ float tile[64 * 65];
  const int t = threadIdx.x, b = blockIdx.x;
  const int k0 = (b >> 4) * 64, n0 = (b & 15) * 64;
#pragma unroll
  for (int i = 0; i < 16; ++i) {
    const int e = t + i * 256, r = e >> 6, c = e & 63;
    tile[r * 65 + c] = W1[(size_t)(k0 + r) * N1 + n0 + c];
  }
  __syncthreads();
#pragma unroll
  for (int i = 0; i < 16; ++i) {
    const int e = t + i * 256, kx = e & 63, ny = e >> 6;
    W1T[(size_t)(n0 + ny) * K1 + k0 + kx] = f2bf(tile[kx * 65 + ny]);
  }
}

__global__ __launch_bounds__(256) void w2t_kernel(const float* __restrict__ W2,
                                                  short* __restrict__ W2T) {
  const int idx = blockIdx.x * 256 + threadIdx.x;
  for (int e = idx; e < 64 * N1; e += 16 * 256) {
    const int c = e >> 10, k = e & 1023;
    const float v = (c < NCOL) ? W2[(size_t)k * NCOL + c] : 0.f;
    W2T[(size_t)c * N1 + k] = f2bf(v);
  }
}

// == path 2: 256x256, 16 waves (4/SIMD), whole-tile counted-vmcnt (session best) ==
#define BK2 64
#define NIT (K1 / BK2)      // 48
#define ASLOT (256 * 64)    // shorts per slot per tensor (32 KB)
#define SH2 264             // epilogue stride (shorts)

struct __align__(16) Smem2 {
  union {
    struct { short A[2][ASLOT]; short B[2][ASLOT]; } s;    // 128 KB
    struct { short h[128 * SH2]; short w2t[64 * SH2]; } e; // 101.4 KB
  } u;
};

__global__ __launch_bounds__(1024, 4)
void hoi_fused3(const short* __restrict__ Xb, const short* __restrict__ W1T,
                const float* __restrict__ B1, const short* __restrict__ W2T,
                const float* __restrict__ B2, float* __restrict__ OUT) {
  __shared__ Smem2 sm;
  const int tid  = threadIdx.x;
  const int lane = tid & 63, wid = tid >> 6;      // 16 waves
  const int wr = wid >> 2, wc = wid & 3;          // wave = 64x64 quadrant (4x4 grid)
  const int l15 = lane & 15, g = lane >> 4, l7 = l15 & 7;

  // bijective XCD-grouped swizzle: 512 wgs, 64/XCD, n fastest
  const int bid  = blockIdx.x;
  const int gidx = (bid & 7) * 64 + (bid >> 3);
  const int m_blk = gidx >> 2, n_blk = gidx & 3;
  const int m0 = m_blk * 256, n0 = n_blk * 256;

  // staging: 1 gload16/wave/unit; wave covers rows wid*8..wid*8+7 of each half
  const int srow  = lane >> 3;
  const int sslot = (lane & 7) ^ srow;            // both-sides swizzle (16B slots)
  const short* aP = Xb  + (size_t)(m0 + wid * 8 + srow) * K1 + sslot * 8;
  const short* bP = W1T + (size_t)(n0 + wid * 8 + srow) * K1 + sslot * 8;
  const int dA = (wid * 8) * 64;                  // wave-uniform LDS dest (shorts)

#define I_A0(kt, sl) GLD16(aP + (size_t)(kt) * BK2,                    &sm.u.s.A[sl][dA])
#define I_A1(kt, sl) GLD16(aP + (size_t)128 * K1 + (size_t)(kt) * BK2, &sm.u.s.A[sl][dA + 8192])
#define I_B0(kt, sl) GLD16(bP + (size_t)(kt) * BK2,                    &sm.u.s.B[sl][dA])
#define I_B1(kt, sl) GLD16(bP + (size_t)128 * K1 + (size_t)(kt) * BK2, &sm.u.s.B[sl][dA + 8192])

  // frag-read bases (swizzled slots; row&7 == l7)
  const int aRd = (wr * 64 + l15) * 64;
  const int bRd = (wc * 64 + l15) * 64;
  const int sk0 = ((g)     ^ l7) * 8;
  const int sk1 = ((4 | g) ^ l7) * 8;

  float b1v[4];
#pragma unroll
  for (int nf = 0; nf < 4; ++nf) b1v[nf] = B1[n0 + wc * 64 + nf * 16 + l15];

  f32x4 acc[4][4] = {};

  // prologue: tile 0 (order-insensitive: whole-tile retirement), full drain
  I_A0(0, 0); I_B0(0, 0); I_B1(0, 0); I_A1(0, 0);
  asm volatile("s_waitcnt vmcnt(0)" ::: "memory");
  __builtin_amdgcn_s_barrier();

  for (int t = 0; t < NIT; ++t) {
    const int s  = t & 1, sx = s ^ 1;
    const int tn = (t + 1 < NIT) ? t + 1 : NIT - 1;   // clamped; junk never read

    __builtin_amdgcn_s_barrier();                     // #A: seals reads of tile t-1
    I_A0(tn, sx);                                     // slot sx free since #A
    SBAR();
    asm volatile("s_waitcnt vmcnt(1)" ::: "memory");  // retire ALL of tile t; keep A0(t+1)
    __builtin_amdgcn_s_barrier();                     // #B: tile t visible block-wide
    SBAR();
    I_A1(tn, sx);
    I_B0(tn, sx);
    I_B1(tn, sx);
    SBAR();

    short8 a_[2][2], b_[4][2];

    // ---- reads: A-lo (mf0-1) + B-all; Q0 ----
#pragma unroll
    for (int mf = 0; mf < 2; ++mf) {
      a_[mf][0] = *(const short8*)&sm.u.s.A[s][aRd + mf * 1024 + sk0];
      a_[mf][1] = *(const short8*)&sm.u.s.A[s][aRd + mf * 1024 + sk1];
    }
#pragma unroll
    for (int nf = 0; nf < 4; ++nf) {
      b_[nf][0] = *(const short8*)&sm.u.s.B[s][bRd + nf * 1024 + sk0];
      b_[nf][1] = *(const short8*)&sm.u.s.B[s][bRd + nf * 1024 + sk1];
    }
    asm volatile("s_waitcnt lgkmcnt(0)" ::: "memory");
    SBAR();
    __builtin_amdgcn_s_setprio(1);
#pragma unroll
    for (int mf = 0; mf < 2; ++mf)
#pragma unroll
      for (int nf = 0; nf < 4; ++nf) {
        acc[mf][nf] = MFMA_BF16(a_[mf][0], b_[nf][0], acc[mf][nf]);
        acc[mf][nf] = MFMA_BF16(a_[mf][1], b_[nf][1], acc[mf][nf]);
      }
    __builtin_amdgcn_s_setprio(0);
    SBAR();

    // ---- reads: A-hi (mf2-3) into same regs; Q1 ----
#pragma unroll
    for (int mf = 0; mf < 2; ++mf) {
      a_[mf][0] = *(const short8*)&sm.u.s.A[s][aRd + (2 + mf) * 1024 + sk0];
      a_[mf][1] = *(const short8*)&sm.u.s.A[s][aRd + (2 + mf) * 1024 + sk1];
    }
    asm volatile("s_waitcnt lgkmcnt(0)" ::: "memory");
    SBAR();
    __builtin_amdgcn_s_setprio(1);
#pragma unroll
    for (int mf = 0; mf < 2; ++mf)
#pragma unroll
      for (int nf = 0; nf < 4; ++nf) {
        acc[2 + mf][nf] = MFMA_BF16(a_[mf][0], b_[nf][0], acc[2 + mf][nf]);
        acc[2 + mf][nf] = MFMA_BF16(a_[mf][1], b_[nf][1], acc[2 + mf][nf]);
      }
    __builtin_amdgcn_s_setprio(0);
    SBAR();
  }
#undef I_A0
#undef I_A1
#undef I_B0
#undef I_B1

  // ---- epilogue: two 128-row phases, 16 waves ----
  for (int ph = 0; ph < 2; ++ph) {
    __syncthreads();   // full drain (vmcnt0+lgkm0): junk DMA landed; prior reads sealed

    if ((wr >> 1) == ph) {   // 8 waves (wr in {2ph,2ph+1}) write their 64x64 quadrant
      const int rbase = (wr & 1) * 64;
#pragma unroll
      for (int mf = 0; mf < 4; ++mf)
#pragma unroll
        for (int nf = 0; nf < 4; ++nf) {
          const int c = wc * 64 + nf * 16 + l15;
#pragma unroll
          for (int j = 0; j < 4; ++j) {
            const int r = rbase + mf * 16 + g * 4 + j;
            sm.u.e.h[r * SH2 + c] = f2bf(fmaxf(acc[mf][nf][j] + b1v[nf], 0.f));
          }
        }
    }
    if (ph == 0) {     // stage w2t[64][256] slice: 1024 threads x 16 shorts
      const int c = tid >> 4, k0c = (tid & 15) * 16;
      *(short8*)&sm.u.e.w2t[c * SH2 + k0c + 0] =
          *(const short8*)&W2T[(size_t)c * N1 + n0 + k0c + 0];
      *(short8*)&sm.u.e.w2t[c * SH2 + k0c + 8] =
          *(const short8*)&W2T[(size_t)c * N1 + n0 + k0c + 8];
    }
    __syncthreads();

    // GEMM2: 128 rows x 50 cols, K = 256; wave = 16 rows x 32-col half
    const int rg = wid >> 1, nh = wid & 1;
    f32x4 acc2[2] = {};
#pragma unroll
    for (int ks = 0; ks < 8; ++ks) {
      const short8 a2 = *(const short8*)&sm.u.e.h[(rg * 16 + l15) * SH2 + ks * 32 + g * 8];
#pragma unroll
      for (int nfl = 0; nfl < 2; ++nfl) {
        const short8 b2 =
            *(const short8*)&sm.u.e.w2t[(nh * 32 + nfl * 16 + l15) * SH2 + ks * 32 + g * 8];
        acc2[nfl] = MFMA_BF16(a2, b2, acc2[nfl]);
      }
    }
#pragma unroll
    for (int nfl = 0; nfl < 2; ++nfl) {
      const int c = nh * 32 + nfl * 16 + l15;
      if (c < NCOL) {
#pragma unroll
        for (int j = 0; j < 4; ++j) {
          const int r = m0 + ph * 128 + rg * 16 + g * 4 + j;
          float v = acc2[nfl][j];
          if (n_blk == 0) v += B2[c];
          atomicAdd(&OUT[(size_t)r * NCOL + c], v);
        }
      }
    }
  }
}

// ================= path 0: R5 fallback (no ws) =================
#define BK 32
#define NSTEP (K1 / BK)
#define SAS 40
#define SHS 136

struct __align__(16) Smem0 {
  union {
    struct { short A[128 * SAS]; short BT[128 * SAS]; } s[2];
    struct { short h[64 * SHS]; short w2t[64 * SHS]; } e;
  } u;
};

__global__ __launch_bounds__(256, 3)
void hoi_fused0(const float* __restrict__ X, const float* __restrict__ W1,
                const float* __restrict__ B1, const float* __restrict__ W2,
                const float* __restrict__ B2, float* __restrict__ OUT) {
  __shared__ Smem0 sm;
  const int tid  = threadIdx.x;
  const int lane = tid & 63, wid = tid >> 6;
  const int wr = wid >> 1, wc = wid & 1;
  const int l15 = lane & 15, g = lane >> 4;
  const int bid   = blockIdx.x;
  const int xcd   = bid & 7, o = bid >> 3;
  const int m_blk = xcd * 32 + (o >> 3);
  const int n_blk = o & 7;
  const int m0 = m_blk * 128, n0 = n_blk * 128;

  const int arow = tid >> 1;
  const int akc  = (tid & 1) << 4;
  const float* aptr = X + (size_t)(m0 + arow) * K1 + akc;
  const int bk2 = tid >> 4, bcm = tid & 15;
  const float* bptr = W1 + (size_t)(2 * bk2) * N1 + n0 + bcm;

  float b1v[4];
#pragma unroll
  for (int nt = 0; nt < 4; ++nt) b1v[nt] = B1[n0 + wc * 64 + nt * 16 + l15];

  f32x4 acc[4][4] = {};
  float4 ra[4];
  float  rb0[8], rb1[8];
#pragma unroll
  for (int q = 0; q < 4; ++q) ra[q] = *(const float4*)(aptr + 4 * q);
#pragma unroll
  for (int i = 0; i < 8; ++i) { rb0[i] = bptr[16 * i]; rb1[i] = bptr[N1 + 16 * i]; }

  for (int step = 0; step < NSTEP; ++step) {
    const int cb = step & 1;
    const short8 av0 = cvt8(ra[0], ra[1]);
    const short8 av1 = cvt8(ra[2], ra[3]);
    unsigned bpk[8];
#pragma unroll
    for (int i = 0; i < 8; ++i)
      bpk[i] = bfr(rb0[i]) | ((__builtin_bit_cast(unsigned, rb1[i]) + 0x8000u) & 0xFFFF0000u);
    if (step + 1 < NSTEP) {
      const int k0v = (step + 1) * BK;
#pragma unroll
      for (int q = 0; q < 4; ++q) ra[q] = *(const float4*)(aptr + k0v + 4 * q);
      const float* bp = bptr + (size_t)k0v * N1;
#pragma unroll
      for (int i = 0; i < 8; ++i) { rb0[i] = bp[16 * i]; rb1[i] = bp[N1 + 16 * i]; }
    }
    *(short8*)&sm.u.s[cb].A[arow * SAS + akc + 0] = av0;
    *(short8*)&sm.u.s[cb].A[arow * SAS + akc + 8] = av1;
#pragma unroll
    for (int i = 0; i < 8; ++i)
      *(unsigned*)&sm.u.s[cb].BT[(bcm + 16 * i) * SAS + 2 * bk2] = bpk[i];

    asm volatile("s_waitcnt lgkmcnt(0)" ::: "memory");
    __builtin_amdgcn_s_barrier();
    __builtin_amdgcn_sched_barrier(0);

    short8 af[4];
#pragma unroll
    for (int mt = 0; mt < 4; ++mt)
      af[mt] = *(const short8*)&sm.u.s[cb].A[(wr * 64 + mt * 16 + l15) * SAS + g * 8];
#pragma unroll
    for (int nt = 0; nt < 4; ++nt) {
      short8 bfv = *(const short8*)&sm.u.s[cb].BT[(wc * 64 + nt * 16 + l15) * SAS + g * 8];
#pragma unroll
      for (int mt = 0; mt < 4; ++mt)
        acc[mt][nt] = MFMA_BF16(af[mt], bfv, acc[mt][nt]);
    }
  }

  for (int p = 0; p < 2; ++p) {
    __syncthreads();
    if (wr == p) {
#pragma unroll
      for (int mt = 0; mt < 4; ++mt)
#pragma unroll
        for (int nt = 0; nt < 4; ++nt) {
          const int c = wc * 64 + nt * 16 + l15;
#pragma unroll
          for (int j = 0; j < 4; ++j) {
            const int r = mt * 16 + g * 4 + j;
            sm.u.e.h[r * SHS + c] = f2bf(fmaxf(acc[mt][nt][j] + b1v[nt], 0.f));
          }
        }
    }
    if (p == 0) {
      const int kk = tid >> 1, ch = (tid & 1) * 32;
#pragma unroll
      for (int i = 0; i < 32; ++i) {
        const int c = ch + i;
        const float v = (c < NCOL) ? W2[(size_t)(n0 + kk) * NCOL + c] : 0.f;
        sm.u.e.w2t[c * SHS + kk] = f2bf(v);
      }
    }
    __syncthreads();

    f32x4 acc2[4] = {};
#pragma unroll
    for (int ks = 0; ks < 4; ++ks) {
      const short8 a2f = *(const short8*)&sm.u.e.h[(wid * 16 + l15) * SHS + ks * 32 + g * 8];
#pragma unroll
      for (int nt2 = 0; nt2 < 4; ++nt2) {
        const short8 b2f = *(const short8*)&sm.u.e.w2t[(nt2 * 16 + l15) * SHS + ks * 32 + g * 8];
        acc2[nt2] = MFMA_BF16(a2f, b2f, acc2[nt2]);
      }
    }
#pragma unroll
    for (int nt2 = 0; nt2 < 4; ++nt2) {
      const int c = nt2 * 16 + l15;
      if (c < NCOL) {
#pragma unroll
        for (int j = 0; j < 4; ++j) {
          const int r = m0 + p * 64 + wid * 16 + g * 4 + j;
          float v = acc2[nt2][j];
          if (n_blk == 0) v += B2[c];
          atomicAdd(&OUT[(size_t)r * NCOL + c], v);
        }
      }
    }
  }
}

extern "C" void kernel_launch(void* const* d_in, const int* in_sizes, int n_in,
                              void* d_out, int out_size, void* d_ws, size_t ws_size,
                              hipStream_t stream) {
  const float* X  = (const float*)d_in[0];
  const float* W1 = (const float*)d_in[1];
  const float* B1 = (const float*)d_in[2];
  const float* W2 = (const float*)d_in[3];
  const float* B2 = (const float*)d_in[4];
  float* OUT = (float*)d_out;

  const size_t XB_BYTES  = (size_t)32768 * K1 * 2;   // 201,326,592
  const size_t W1T_BYTES = (size_t)N1 * K1 * 2;      // 6,291,456
  const size_t W2T_BYTES = (size_t)64 * N1 * 2;      // 131,072

  hipMemsetAsync(d_out, 0, (size_t)out_size * sizeof(float), stream);

  if (ws_size >= XB_BYTES + W1T_BYTES + W2T_BYTES) {
    short* Xb  = (short*)d_ws;
    short* W1T = (short*)((char*)d_ws + XB_BYTES);
    short* W2T = (short*)((char*)d_ws + XB_BYTES + W1T_BYTES);
    hipLaunchKernelGGL(xcvt_kernel, dim3(2048), dim3(512), 0, stream, X, Xb);
    hipLaunchKernelGGL(w1t_kernel, dim3(768), dim3(256), 0, stream, W1, W1T);
    hipLaunchKernelGGL(w2t_kernel, dim3(16), dim3(256), 0, stream, W2, W2T);
    hipLaunchKernelGGL(hoi_fused3, dim3(512), dim3(1024), 0, stream, Xb, W1T, B1, W2T, B2, OUT);
  } else {
    hipLaunchKernelGGL(hoi_fused0, dim3(2048), dim3(256), 0, stream, X, W1, B1, W2, B2, OUT);
  }
}